// Round 4
// baseline (359.106 us; speedup 1.0000x reference)
//
#include <hip/hip_runtime.h>
#include <cstdint>
#include <cstddef>

#define N_    32
#define C_    256
#define H_    56
#define W_    56
#define HW_   (H_ * W_)      // 3136
#define NHW_  (N_ * HW_)     // 100352
#define COUT_ 256
#define EPS_  1e-4f
#define PW_   58             // padded width
#define PIMG_ (PW_ * PW_)    // 3364 padded pixels per image

// ---------------------------------------------------------------------------
// Kernel 1a: BN partial sums. 2048 blocks = (c, slice of 4 images).
// ---------------------------------------------------------------------------
__global__ void k_bn_partial(const float* __restrict__ x,
                             float* __restrict__ ps, float* __restrict__ pq) {
    const int c = blockIdx.x >> 3;
    const int s = blockIdx.x & 7;
    const int t = threadIdx.x;
    float sm = 0.f, sq = 0.f;
    for (int n = s * 4; n < s * 4 + 4; ++n) {
        const float4* p = (const float4*)(x + (size_t)(n * C_ + c) * HW_);
        for (int i = t; i < HW_ / 4; i += 256) {
            float4 v = p[i];
            sm += v.x + v.y + v.z + v.w;
            sq += v.x * v.x + v.y * v.y + v.z * v.z + v.w * v.w;
        }
    }
    __shared__ float ls[256], lq[256];
    ls[t] = sm; lq[t] = sq;
    __syncthreads();
    for (int off = 128; off >= 1; off >>= 1) {
        if (t < off) { ls[t] += ls[t + off]; lq[t] += lq[t + off]; }
        __syncthreads();
    }
    if (t == 0) { ps[s * C_ + c] = ls[0]; pq[s * C_ + c] = lq[0]; }
}

// ---------------------------------------------------------------------------
// Kernel 1b: finalize per-channel affine: xn = x*a[c] + bb[c]
// ---------------------------------------------------------------------------
__global__ void k_bn_final(const float* __restrict__ ps, const float* __restrict__ pq,
                           const float* __restrict__ gamma, const float* __restrict__ beta,
                           float* __restrict__ a, float* __restrict__ bb) {
    const int c = threadIdx.x;
    float sm = 0.f, sq = 0.f;
    for (int s = 0; s < 8; ++s) { sm += ps[s * C_ + c]; sq += pq[s * C_ + c]; }
    float mu   = sm * (1.f / NHW_);
    float var  = sq * (1.f / NHW_) - mu * mu;
    float rstd = rsqrtf(var + EPS_);
    float g    = gamma[c] * rstd;
    a[c]  = g;
    bb[c] = beta[c] - mu * g;
}

// ---------------------------------------------------------------------------
// Kernel 2: weight prep. alpha, bit-pack sign(W) into PLANAR layout
// wbits[wd][co][t] (9 contiguous u64 per (wd,co) -> single s_load burst in
// k_conv), and border-correction table ctab[cls][co].
// ---------------------------------------------------------------------------
__global__ void k_wpack(const float* __restrict__ Wt, float* __restrict__ alpha,
                        uint64_t* __restrict__ wbits, int* __restrict__ ctab) {
    const int co = blockIdx.x;
    const int ci = threadIdx.x;
    const int lane = ci & 63, wave = ci >> 6;      // wave == channel-word wd
    const float* p = Wt + (size_t)(co * C_ + ci) * 9;
    float wv[9];
    float asum = 0.f;
#pragma unroll
    for (int t = 0; t < 9; ++t) { wv[t] = p[t]; asum += fabsf(wv[t]); }
    __shared__ int Pl[9];
    if (ci < 9) Pl[ci] = 0;
    __syncthreads();
#pragma unroll
    for (int t = 0; t < 9; ++t) {
        uint64_t mask = __ballot(wv[t] > 0.f);
        if (lane == 0) {
            wbits[((size_t)wave * COUT_ + co) * 9 + t] = mask;   // planar [wd][co][t]
            atomicAdd(&Pl[t], (int)__popcll(mask));
        }
    }
    __shared__ float red[256];
    red[ci] = asum;
    __syncthreads();                       // also publishes Pl
    for (int off = 128; off >= 1; off >>= 1) {
        if (ci < off) red[ci] += red[ci + off];
        __syncthreads();
    }
    if (ci == 0) alpha[co] = red[0] * (1.f / 2304.f);
    if (ci < 9) {
        const int rc = ci / 3, cc = ci % 3;
        unsigned m9 = (rc == 0 ? 0x007u : 0u) | (rc == 2 ? 0x1C0u : 0u)
                    | (cc == 0 ? 0x049u : 0u) | (cc == 2 ? 0x124u : 0u);
        int s = 0;
#pragma unroll
        for (int t = 0; t < 9; ++t)
            if ((m9 >> t) & 1) s += 2 * Pl[t] - 256;
        ctab[ci * 256 + co] = s;
    }
}

// ---------------------------------------------------------------------------
// Kernel 3: fused normalize + |xn| partial channel-mean + sign bit-pack into
// PLANAR padded layout xbits[wd][n][58][58] (borders pre-zeroed by memset).
// grid.y = which 64-channel word this block handles.
// ---------------------------------------------------------------------------
__global__ void k_mpack(const float* __restrict__ x, const float* __restrict__ a,
                        const float* __restrict__ bb, uint64_t* __restrict__ xbits,
                        float* __restrict__ m) {
    const int p = blockIdx.x * 256 + threadIdx.x;
    const int wd = blockIdx.y;          // 64-channel word index 0..3
    const int n = p / HW_;
    const int hw = p - n * HW_;
    const int h = hw / W_;
    const int w = hw - h * W_;
    const float* xp = x + (size_t)n * C_ * HW_ + (size_t)(wd * 64) * HW_ + hw;
    float macc = 0.f;
    uint64_t bw = 0;
#pragma unroll
    for (int j = 0; j < 64; ++j) {
        const int c = wd * 64 + j;
        float xn = fmaf(xp[(size_t)j * HW_], a[c], bb[c]);
        macc += fabsf(xn);
        bw |= (xn > 0.f) ? (1ull << j) : 0ull;
    }
    xbits[((size_t)wd * N_ + n) * PIMG_ + (size_t)(h + 1) * PW_ + (w + 1)] = bw;
    atomicAdd(&m[p], macc * (1.f / C_));
}

// ---------------------------------------------------------------------------
// Kernel 3b: 3x3 box filter (zero-padded, /9) on m -> beta_map
// ---------------------------------------------------------------------------
__global__ void k_box(const float* __restrict__ m, float* __restrict__ beta_map) {
    const int idx = blockIdx.x * 256 + threadIdx.x;
    if (idx >= NHW_) return;
    const int w = idx % W_;
    const int h = (idx / W_) % H_;
    const int n = idx / HW_;
    const float* mp = m + (size_t)n * HW_;
    float s = 0.f;
#pragma unroll
    for (int dh = 0; dh < 3; ++dh) {
        int ih = h + dh - 1;
        if (ih < 0 || ih >= H_) continue;
#pragma unroll
        for (int dw = 0; dw < 3; ++dw) {
            int iw = w + dw - 1;
            if (iw < 0 || iw >= W_) continue;
            s += mp[ih * W_ + iw];
        }
    }
    beta_map[idx] = s * (1.f / 9.f);
}

// ---------------------------------------------------------------------------
// Kernel 4: binary conv, LOOP-INTERCHANGED. Rounds 0-3 kept a 36-u64 window
// live across a 64-iteration cout loop; the allocator refused to give it
// arch VGPRs (VGPR_Count 44-48 every round) and paid ~2.3x the VALU floor in
// register shuffling. New structure makes the PERSISTENT array the 64
// per-cout accumulators (statically indexed, 64 VGPRs) and the x-window
// SHORT-LIVED: outer wd pass (runtime loop, #pragma unroll 1) loads a 9-u64
// slice (18 VGPRs, live one pass), streams 9-contiguous wave-uniform weights
// via SMEM, accumulates popcounts. Live set ~100 regs < 128 budget of
// (256,4); unrolled body ~14 KB fits I$.
// ---------------------------------------------------------------------------
__global__ void __launch_bounds__(256, 4)
k_conv(const uint64_t* __restrict__ xbits, const uint64_t* __restrict__ wbits,
       const int* __restrict__ ctab, const float* __restrict__ beta_map,
       const float* __restrict__ alpha, const float* __restrict__ bias,
       float* __restrict__ out) {
    const int p   = blockIdx.x * 256 + (int)threadIdx.x;  // flat pixel
    const int grp = blockIdx.y;                            // cout group of 64
    const int n  = p / HW_;
    const int hw = p - n * HW_;
    const int h  = hw / W_;
    const int w  = hw - h * W_;

    int acc[64];
#pragma unroll
    for (int i = 0; i < 64; ++i) acc[i] = 0;

#pragma unroll 1
    for (int wd = 0; wd < 4; ++wd) {
        // 9-u64 window slice for this channel-word (padded plane: rows of 3
        // contiguous u64). (h,w) indexes the padded top-left corner directly.
        const uint64_t* xp = xbits + ((size_t)wd * N_ + n) * PIMG_ + (size_t)h * PW_ + w;
        const uint64_t x0 = xp[0],           x1 = xp[1],            x2 = xp[2];
        const uint64_t x3 = xp[PW_],         x4 = xp[PW_ + 1],      x5 = xp[PW_ + 2];
        const uint64_t x6 = xp[2 * PW_],     x7 = xp[2 * PW_ + 1],  x8 = xp[2 * PW_ + 2];

        const uint64_t* wq = wbits + ((size_t)wd * COUT_ + grp * 64) * 9;
#pragma unroll
        for (int coi = 0; coi < 64; ++coi) {
            const uint64_t* wr = wq + coi * 9;   // wave-uniform, 9 contiguous u64
            int s = (int)__popcll(x0 ^ wr[0]) + (int)__popcll(x1 ^ wr[1])
                  + (int)__popcll(x2 ^ wr[2]) + (int)__popcll(x3 ^ wr[3])
                  + (int)__popcll(x4 ^ wr[4]) + (int)__popcll(x5 ^ wr[5])
                  + (int)__popcll(x6 ^ wr[6]) + (int)__popcll(x7 ^ wr[7])
                  + (int)__popcll(x8 ^ wr[8]);
            acc[coi] += s;
        }
    }

    const int rowcls = (h == 0) ? 0 : ((h == H_ - 1) ? 2 : 1);
    const int colcls = (w == 0) ? 0 : ((w == W_ - 1) ? 2 : 1);
    const int* crow = ctab + (rowcls * 3 + colcls) * 256 + grp * 64;
    const float bm = beta_map[p];
    float* op = out + (size_t)n * COUT_ * HW_ + (size_t)(grp * 64) * HW_ + hw;

#pragma unroll
    for (int coi = 0; coi < 64; ++coi) {
        const int co = grp * 64 + coi;
        const int dot = 2304 - 2 * acc[coi] + crow[coi];
        float o = ((float)dot + bias[co]) * bm * alpha[co];
        o = fmaxf(o, 0.f);
        op[(size_t)coi * HW_] = o;
    }
}

// ---------------------------------------------------------------------------
// Workspace layout (bytes):
//   ps       @ 0        8192
//   pq       @ 8192     8192
//   a        @ 16384    1024
//   bb       @ 17408    1024
//   alpha    @ 18432    1024
//   ctab     @ 19456    9216
//   wbits    @ 28672    73728     (planar [wd][co][9] u64)
//   xbits    @ 102400   3444736   (planar [wd][32][58][58] u64, memset 0)
//   m        @ 3547136  401408    (zeroed via memset; atomic-accumulated)
//   beta_map @ 3948544  401408
//   total    4349952
// ---------------------------------------------------------------------------
extern "C" void kernel_launch(void* const* d_in, const int* in_sizes, int n_in,
                              void* d_out, int out_size, void* d_ws, size_t ws_size,
                              hipStream_t stream) {
    (void)in_sizes; (void)n_in; (void)out_size; (void)ws_size;
    const float* x     = (const float*)d_in[0];
    const float* gamma = (const float*)d_in[1];
    const float* betab = (const float*)d_in[2];
    const float* Wt    = (const float*)d_in[3];
    const float* b     = (const float*)d_in[4];
    float* out = (float*)d_out;

    uint8_t* base = (uint8_t*)d_ws;
    float*    ps       = (float*)(base + 0);
    float*    pq       = (float*)(base + 8192);
    float*    a        = (float*)(base + 16384);
    float*    bb       = (float*)(base + 17408);
    float*    alpha    = (float*)(base + 18432);
    int*      ctab     = (int*)(base + 19456);
    uint64_t* wbits    = (uint64_t*)(base + 28672);
    uint64_t* xbits    = (uint64_t*)(base + 102400);
    float*    m        = (float*)(base + 3547136);
    float*    beta_map = (float*)(base + 3948544);

    k_bn_partial<<<2048, 256, 0, stream>>>(x, ps, pq);
    k_bn_final<<<1, 256, 0, stream>>>(ps, pq, gamma, betab, a, bb);
    k_wpack<<<COUT_, 256, 0, stream>>>(Wt, alpha, wbits, ctab);
    hipMemsetAsync(xbits, 0, (size_t)N_ * PIMG_ * 4 * sizeof(uint64_t), stream);
    hipMemsetAsync(m, 0, (size_t)NHW_ * sizeof(float), stream);
    k_mpack<<<dim3(NHW_ / 256, 4), 256, 0, stream>>>(x, a, bb, xbits, m);
    k_box<<<(NHW_ + 255) / 256, 256, 0, stream>>>(m, beta_map);
    k_conv<<<dim3(NHW_ / 256, 4), 256, 0, stream>>>(xbits, wbits, ctab, beta_map, alpha, b, out);
}

// Round 5
// 346.196 us; speedup vs baseline: 1.0373x; 1.0373x over previous
//
#include <hip/hip_runtime.h>
#include <cstdint>
#include <cstddef>

#define N_    32
#define C_    256
#define H_    56
#define W_    56
#define HW_   (H_ * W_)      // 3136
#define NHW_  (N_ * HW_)     // 100352
#define COUT_ 256
#define EPS_  1e-4f
#define PW_   58             // padded width
#define PIMG_ (PW_ * PW_)    // 3364 padded pixels per image

// ---------------------------------------------------------------------------
// Kernel 1a: BN partial sums. 2048 blocks = (c, slice of 4 images).
// ---------------------------------------------------------------------------
__global__ void k_bn_partial(const float* __restrict__ x,
                             float* __restrict__ ps, float* __restrict__ pq) {
    const int c = blockIdx.x >> 3;
    const int s = blockIdx.x & 7;
    const int t = threadIdx.x;
    float sm = 0.f, sq = 0.f;
    for (int n = s * 4; n < s * 4 + 4; ++n) {
        const float4* p = (const float4*)(x + (size_t)(n * C_ + c) * HW_);
        for (int i = t; i < HW_ / 4; i += 256) {
            float4 v = p[i];
            sm += v.x + v.y + v.z + v.w;
            sq += v.x * v.x + v.y * v.y + v.z * v.z + v.w * v.w;
        }
    }
    __shared__ float ls[256], lq[256];
    ls[t] = sm; lq[t] = sq;
    __syncthreads();
    for (int off = 128; off >= 1; off >>= 1) {
        if (t < off) { ls[t] += ls[t + off]; lq[t] += lq[t + off]; }
        __syncthreads();
    }
    if (t == 0) { ps[s * C_ + c] = ls[0]; pq[s * C_ + c] = lq[0]; }
}

// ---------------------------------------------------------------------------
// Kernel 1b: finalize per-channel affine: xn = x*a[c] + bb[c]
// ---------------------------------------------------------------------------
__global__ void k_bn_final(const float* __restrict__ ps, const float* __restrict__ pq,
                           const float* __restrict__ gamma, const float* __restrict__ beta,
                           float* __restrict__ a, float* __restrict__ bb) {
    const int c = threadIdx.x;
    float sm = 0.f, sq = 0.f;
    for (int s = 0; s < 8; ++s) { sm += ps[s * C_ + c]; sq += pq[s * C_ + c]; }
    float mu   = sm * (1.f / NHW_);
    float var  = sq * (1.f / NHW_) - mu * mu;
    float rstd = rsqrtf(var + EPS_);
    float g    = gamma[c] * rstd;
    a[c]  = g;
    bb[c] = beta[c] - mu * g;
}

// ---------------------------------------------------------------------------
// Kernel 2: weight prep. alpha, bit-pack sign(W) into layout wbits[co][wd][t]
// (36 contiguous u64 per cout, wd-major to match the planar window order ->
// one 288-B s_load burst per cout in k_conv), and border table ctab[cls][co].
// ---------------------------------------------------------------------------
__global__ void k_wpack(const float* __restrict__ Wt, float* __restrict__ alpha,
                        uint64_t* __restrict__ wbits, int* __restrict__ ctab) {
    const int co = blockIdx.x;
    const int ci = threadIdx.x;
    const int lane = ci & 63, wave = ci >> 6;      // wave == channel-word wd
    const float* p = Wt + (size_t)(co * C_ + ci) * 9;
    float wv[9];
    float asum = 0.f;
#pragma unroll
    for (int t = 0; t < 9; ++t) { wv[t] = p[t]; asum += fabsf(wv[t]); }
    __shared__ int Pl[9];
    if (ci < 9) Pl[ci] = 0;
    __syncthreads();
#pragma unroll
    for (int t = 0; t < 9; ++t) {
        uint64_t mask = __ballot(wv[t] > 0.f);
        if (lane == 0) {
            wbits[((size_t)co * 4 + wave) * 9 + t] = mask;   // [co][wd][t]
            atomicAdd(&Pl[t], (int)__popcll(mask));
        }
    }
    __shared__ float red[256];
    red[ci] = asum;
    __syncthreads();                       // also publishes Pl
    for (int off = 128; off >= 1; off >>= 1) {
        if (ci < off) red[ci] += red[ci + off];
        __syncthreads();
    }
    if (ci == 0) alpha[co] = red[0] * (1.f / 2304.f);
    if (ci < 9) {
        const int rc = ci / 3, cc = ci % 3;
        unsigned m9 = (rc == 0 ? 0x007u : 0u) | (rc == 2 ? 0x1C0u : 0u)
                    | (cc == 0 ? 0x049u : 0u) | (cc == 2 ? 0x124u : 0u);
        int s = 0;
#pragma unroll
        for (int t = 0; t < 9; ++t)
            if ((m9 >> t) & 1) s += 2 * Pl[t] - 256;
        ctab[ci * 256 + co] = s;
    }
}

// ---------------------------------------------------------------------------
// Kernel 3: fused normalize + |xn| partial channel-mean + sign bit-pack into
// PLANAR padded layout xbits[wd][n][58][58] (borders pre-zeroed by memset).
// grid.y = which 64-channel word this block handles. (Planar layout kept
// from r4: coalesced 8B-stride writes cut non-conv time ~45 us.)
// ---------------------------------------------------------------------------
__global__ void k_mpack(const float* __restrict__ x, const float* __restrict__ a,
                        const float* __restrict__ bb, uint64_t* __restrict__ xbits,
                        float* __restrict__ m) {
    const int p = blockIdx.x * 256 + threadIdx.x;
    const int wd = blockIdx.y;          // 64-channel word index 0..3
    const int n = p / HW_;
    const int hw = p - n * HW_;
    const int h = hw / W_;
    const int w = hw - h * W_;
    const float* xp = x + (size_t)n * C_ * HW_ + (size_t)(wd * 64) * HW_ + hw;
    float macc = 0.f;
    uint64_t bw = 0;
#pragma unroll
    for (int j = 0; j < 64; ++j) {
        const int c = wd * 64 + j;
        float xn = fmaf(xp[(size_t)j * HW_], a[c], bb[c]);
        macc += fabsf(xn);
        bw |= (xn > 0.f) ? (1ull << j) : 0ull;
    }
    xbits[((size_t)wd * N_ + n) * PIMG_ + (size_t)(h + 1) * PW_ + (w + 1)] = bw;
    atomicAdd(&m[p], macc * (1.f / C_));
}

// ---------------------------------------------------------------------------
// Kernel 3b: 3x3 box filter (zero-padded, /9) on m -> beta_map
// ---------------------------------------------------------------------------
__global__ void k_box(const float* __restrict__ m, float* __restrict__ beta_map) {
    const int idx = blockIdx.x * 256 + threadIdx.x;
    if (idx >= NHW_) return;
    const int w = idx % W_;
    const int h = (idx / W_) % H_;
    const int n = idx / HW_;
    const float* mp = m + (size_t)n * HW_;
    float s = 0.f;
#pragma unroll
    for (int dh = 0; dh < 3; ++dh) {
        int ih = h + dh - 1;
        if (ih < 0 || ih >= H_) continue;
#pragma unroll
        for (int dw = 0; dw < 3; ++dw) {
            int iw = w + dw - 1;
            if (iw < 0 || iw >= W_) continue;
            s += mp[ih * W_ + iw];
        }
    }
    beta_map[idx] = s * (1.f / 9.f);
}

// ---------------------------------------------------------------------------
// Kernel 4: binary conv. lane = flat pixel, grid.y = cout group of 64.
// The two fixes this round (both aimed at the invariant VGPR_Count=48
// disease across r0-r4):
//  (1) #pragma unroll 1 on the coi loop: the AGPR-park / load-remat
//      decision is driven by pressure over the UNROLLED 64-iter body;
//      un-unrolled live set ~100 regs fits the (256,4) 128-reg budget.
//  (2) window pinned by "+v" asm ONCE before the loop (not inside, r3's
//      mistake): asm-defined values cannot be rematerialized from memory,
//      so the compiler must keep them live - and with (1) the cheapest
//      place is arch VGPRs.
// Weights: one contiguous 288-B wave-uniform burst per cout -> s_load.
// ---------------------------------------------------------------------------
#define PIN9(A)  asm volatile("" : "+v"(xw[(A)+0]), "+v"(xw[(A)+1]), "+v"(xw[(A)+2]), \
                                   "+v"(xw[(A)+3]), "+v"(xw[(A)+4]), "+v"(xw[(A)+5]), \
                                   "+v"(xw[(A)+6]), "+v"(xw[(A)+7]), "+v"(xw[(A)+8]))

__global__ void __launch_bounds__(256, 4)
k_conv(const uint64_t* __restrict__ xbits, const uint64_t* __restrict__ wbits,
       const int* __restrict__ ctab, const float* __restrict__ beta_map,
       const float* __restrict__ alpha, const float* __restrict__ bias,
       float* __restrict__ out) {
    const int p   = blockIdx.x * 256 + (int)threadIdx.x;  // flat pixel
    const int grp = blockIdx.y;                            // cout group of 64
    const int n  = p / HW_;
    const int hw = p - n * HW_;
    const int h  = hw / W_;
    const int w  = hw - h * W_;

    // load 3x3x4wd window (36 u64) from the planar padded planes
    uint64_t xw[36];
#pragma unroll
    for (int wd = 0; wd < 4; ++wd) {
        const uint64_t* xp = xbits + ((size_t)wd * N_ + n) * PIMG_ + (size_t)h * PW_ + w;
#pragma unroll
        for (int r = 0; r < 3; ++r) {
            xw[wd * 9 + r * 3 + 0] = xp[r * PW_ + 0];
            xw[wd * 9 + r * 3 + 1] = xp[r * PW_ + 1];
            xw[wd * 9 + r * 3 + 2] = xp[r * PW_ + 2];
        }
    }
    // pin ONCE: values become asm-defined (non-rematerializable)
    PIN9(0); PIN9(9); PIN9(18); PIN9(27);

    const int rowcls = (h == 0) ? 0 : ((h == H_ - 1) ? 2 : 1);
    const int colcls = (w == 0) ? 0 : ((w == W_ - 1) ? 2 : 1);
    const int* crow = ctab + (rowcls * 3 + colcls) * 256 + grp * 64;
    const float bm = beta_map[p];
    float* op = out + (size_t)n * COUT_ * HW_ + (size_t)(grp * 64) * HW_ + hw;

#pragma unroll 1
    for (int coi = 0; coi < 64; ++coi) {
        const int co = grp * 64 + coi;
        const uint64_t* wq = wbits + (size_t)co * 36;   // wave-uniform -> s_load
        int a0 = 0, a1 = 0, a2 = 0, a3 = 0;
#pragma unroll
        for (int k = 0; k < 9; ++k) {
            a0 += (int)__popcll(xw[k]      ^ wq[k]);
            a1 += (int)__popcll(xw[9 + k]  ^ wq[9 + k]);
            a2 += (int)__popcll(xw[18 + k] ^ wq[18 + k]);
            a3 += (int)__popcll(xw[27 + k] ^ wq[27 + k]);
        }
        const int acc = (a0 + a1) + (a2 + a3);
        const int dot = 2304 - 2 * acc + crow[coi];
        float o = ((float)dot + bias[co]) * bm * alpha[co];
        o = fmaxf(o, 0.f);
        op[(size_t)coi * HW_] = o;
    }
}

// ---------------------------------------------------------------------------
// Workspace layout (bytes):
//   ps       @ 0        8192
//   pq       @ 8192     8192
//   a        @ 16384    1024
//   bb       @ 17408    1024
//   alpha    @ 18432    1024
//   ctab     @ 19456    9216
//   wbits    @ 28672    73728     ([co][wd][9] u64, 288 B contiguous per co)
//   xbits    @ 102400   3444736   (planar [wd][32][58][58] u64, memset 0)
//   m        @ 3547136  401408    (zeroed via memset; atomic-accumulated)
//   beta_map @ 3948544  401408
//   total    4349952
// ---------------------------------------------------------------------------
extern "C" void kernel_launch(void* const* d_in, const int* in_sizes, int n_in,
                              void* d_out, int out_size, void* d_ws, size_t ws_size,
                              hipStream_t stream) {
    (void)in_sizes; (void)n_in; (void)out_size; (void)ws_size;
    const float* x     = (const float*)d_in[0];
    const float* gamma = (const float*)d_in[1];
    const float* betab = (const float*)d_in[2];
    const float* Wt    = (const float*)d_in[3];
    const float* b     = (const float*)d_in[4];
    float* out = (float*)d_out;

    uint8_t* base = (uint8_t*)d_ws;
    float*    ps       = (float*)(base + 0);
    float*    pq       = (float*)(base + 8192);
    float*    a        = (float*)(base + 16384);
    float*    bb       = (float*)(base + 17408);
    float*    alpha    = (float*)(base + 18432);
    int*      ctab     = (int*)(base + 19456);
    uint64_t* wbits    = (uint64_t*)(base + 28672);
    uint64_t* xbits    = (uint64_t*)(base + 102400);
    float*    m        = (float*)(base + 3547136);
    float*    beta_map = (float*)(base + 3948544);

    k_bn_partial<<<2048, 256, 0, stream>>>(x, ps, pq);
    k_bn_final<<<1, 256, 0, stream>>>(ps, pq, gamma, betab, a, bb);
    k_wpack<<<COUT_, 256, 0, stream>>>(Wt, alpha, wbits, ctab);
    hipMemsetAsync(xbits, 0, (size_t)N_ * PIMG_ * 4 * sizeof(uint64_t), stream);
    hipMemsetAsync(m, 0, (size_t)NHW_ * sizeof(float), stream);
    k_mpack<<<dim3(NHW_ / 256, 4), 256, 0, stream>>>(x, a, bb, xbits, m);
    k_box<<<(NHW_ + 255) / 256, 256, 0, stream>>>(m, beta_map);
    k_conv<<<dim3(NHW_ / 256, 4), 256, 0, stream>>>(xbits, wbits, ctab, beta_map, alpha, b, out);
}

// Round 7
// 318.528 us; speedup vs baseline: 1.1274x; 1.0869x over previous
//
#include <hip/hip_runtime.h>
#include <cstdint>
#include <cstddef>

#define N_    32
#define C_    256
#define H_    56
#define W_    56
#define HW_   (H_ * W_)      // 3136
#define NHW_  (N_ * HW_)     // 100352
#define COUT_ 256
#define EPS_  1e-4f
#define PW_   58             // padded width
#define PIMG_ (PW_ * PW_)    // 3364 padded pixels per image

// ---------------------------------------------------------------------------
// Kernel 1a: BN partial sums. 2048 blocks = (c, slice of 4 images).
// ---------------------------------------------------------------------------
__global__ void k_bn_partial(const float* __restrict__ x,
                             float* __restrict__ ps, float* __restrict__ pq) {
    const int c = blockIdx.x >> 3;
    const int s = blockIdx.x & 7;
    const int t = threadIdx.x;
    float sm = 0.f, sq = 0.f;
    for (int n = s * 4; n < s * 4 + 4; ++n) {
        const float4* p = (const float4*)(x + (size_t)(n * C_ + c) * HW_);
        for (int i = t; i < HW_ / 4; i += 256) {
            float4 v = p[i];
            sm += v.x + v.y + v.z + v.w;
            sq += v.x * v.x + v.y * v.y + v.z * v.z + v.w * v.w;
        }
    }
    __shared__ float ls[256], lq[256];
    ls[t] = sm; lq[t] = sq;
    __syncthreads();
    for (int off = 128; off >= 1; off >>= 1) {
        if (t < off) { ls[t] += ls[t + off]; lq[t] += lq[t + off]; }
        __syncthreads();
    }
    if (t == 0) { ps[s * C_ + c] = ls[0]; pq[s * C_ + c] = lq[0]; }
}

// ---------------------------------------------------------------------------
// Kernel 1b: finalize per-channel affine: xn = x*a[c] + bb[c]
// ---------------------------------------------------------------------------
__global__ void k_bn_final(const float* __restrict__ ps, const float* __restrict__ pq,
                           const float* __restrict__ gamma, const float* __restrict__ beta,
                           float* __restrict__ a, float* __restrict__ bb) {
    const int c = threadIdx.x;
    float sm = 0.f, sq = 0.f;
    for (int s = 0; s < 8; ++s) { sm += ps[s * C_ + c]; sq += pq[s * C_ + c]; }
    float mu   = sm * (1.f / NHW_);
    float var  = sq * (1.f / NHW_) - mu * mu;
    float rstd = rsqrtf(var + EPS_);
    float g    = gamma[c] * rstd;
    a[c]  = g;
    bb[c] = beta[c] - mu * g;
}

// ---------------------------------------------------------------------------
// Kernel 2: weight prep. alpha, bit-pack sign(W) into layout wbits[co][wd][t]
// (36 contiguous u64 per cout -> s_load bursts in k_conv), and border table
// ctab[cls][co].
// ---------------------------------------------------------------------------
__global__ void k_wpack(const float* __restrict__ Wt, float* __restrict__ alpha,
                        uint64_t* __restrict__ wbits, int* __restrict__ ctab) {
    const int co = blockIdx.x;
    const int ci = threadIdx.x;
    const int lane = ci & 63, wave = ci >> 6;      // wave == channel-word wd
    const float* p = Wt + (size_t)(co * C_ + ci) * 9;
    float wv[9];
    float asum = 0.f;
#pragma unroll
    for (int t = 0; t < 9; ++t) { wv[t] = p[t]; asum += fabsf(wv[t]); }
    __shared__ int Pl[9];
    if (ci < 9) Pl[ci] = 0;
    __syncthreads();
#pragma unroll
    for (int t = 0; t < 9; ++t) {
        uint64_t mask = __ballot(wv[t] > 0.f);
        if (lane == 0) {
            wbits[((size_t)co * 4 + wave) * 9 + t] = mask;   // [co][wd][t]
            atomicAdd(&Pl[t], (int)__popcll(mask));
        }
    }
    __shared__ float red[256];
    red[ci] = asum;
    __syncthreads();                       // also publishes Pl
    for (int off = 128; off >= 1; off >>= 1) {
        if (ci < off) red[ci] += red[ci + off];
        __syncthreads();
    }
    if (ci == 0) alpha[co] = red[0] * (1.f / 2304.f);
    if (ci < 9) {
        const int rc = ci / 3, cc = ci % 3;
        unsigned m9 = (rc == 0 ? 0x007u : 0u) | (rc == 2 ? 0x1C0u : 0u)
                    | (cc == 0 ? 0x049u : 0u) | (cc == 2 ? 0x124u : 0u);
        int s = 0;
#pragma unroll
        for (int t = 0; t < 9; ++t)
            if ((m9 >> t) & 1) s += 2 * Pl[t] - 256;
        ctab[ci * 256 + co] = s;
    }
}

// ---------------------------------------------------------------------------
// Kernel 3: fused normalize + |xn| partial channel-mean + sign bit-pack into
// PLANAR padded layout xbits[wd][n][58][58] (borders pre-zeroed by memset).
// grid.y = which 64-channel word this block handles.
// ---------------------------------------------------------------------------
__global__ void k_mpack(const float* __restrict__ x, const float* __restrict__ a,
                        const float* __restrict__ bb, uint64_t* __restrict__ xbits,
                        float* __restrict__ m) {
    const int p = blockIdx.x * 256 + threadIdx.x;
    const int wd = blockIdx.y;          // 64-channel word index 0..3
    const int n = p / HW_;
    const int hw = p - n * HW_;
    const int h = hw / W_;
    const int w = hw - h * W_;
    const float* xp = x + (size_t)n * C_ * HW_ + (size_t)(wd * 64) * HW_ + hw;
    float macc = 0.f;
    uint64_t bw = 0;
#pragma unroll
    for (int j = 0; j < 64; ++j) {
        const int c = wd * 64 + j;
        float xn = fmaf(xp[(size_t)j * HW_], a[c], bb[c]);
        macc += fabsf(xn);
        bw |= (xn > 0.f) ? (1ull << j) : 0ull;
    }
    xbits[((size_t)wd * N_ + n) * PIMG_ + (size_t)(h + 1) * PW_ + (w + 1)] = bw;
    atomicAdd(&m[p], macc * (1.f / C_));
}

// ---------------------------------------------------------------------------
// Kernel 3b: 3x3 box filter (zero-padded, /9) on m -> beta_map
// ---------------------------------------------------------------------------
__global__ void k_box(const float* __restrict__ m, float* __restrict__ beta_map) {
    const int idx = blockIdx.x * 256 + threadIdx.x;
    if (idx >= NHW_) return;
    const int w = idx % W_;
    const int h = (idx / W_) % H_;
    const int n = idx / HW_;
    const float* mp = m + (size_t)n * HW_;
    float s = 0.f;
#pragma unroll
    for (int dh = 0; dh < 3; ++dh) {
        int ih = h + dh - 1;
        if (ih < 0 || ih >= H_) continue;
#pragma unroll
        for (int dw = 0; dw < 3; ++dw) {
            int iw = w + dw - 1;
            if (iw < 0 || iw >= W_) continue;
            s += mp[ih * W_ + iw];
        }
    }
    beta_map[idx] = s * (1.f / 9.f);
}

// ---------------------------------------------------------------------------
// Kernel 4: binary conv — inline-asm core. Six C-level structures (r0-r5)
// all produced the same inflated codegen (VGPR_Count 44-48, ~2.3x the 152
// VALU-ops/output floor): the allocator never keeps the 36-u64 window in
// arch VGPRs and shuttles it around every use. So the xnor-popcount core is
// now dictated per tap-word:
//     v_xor_b32  tmp_lo, s_w_lo, v_x_lo
//     v_xor_b32  tmp_hi, s_w_hi, v_x_hi
//     v_bcnt_u32_b32 acc, tmp_lo, acc      // accumulate is free
//     v_bcnt_u32_b32 acc, tmp_hi, acc
// = exactly 144 VALU per output. "v" inputs force the window into arch
// VGPRs at every use; "s" inputs force weights scalar. 4 independent acc
// chains (one per channel-word) keep bcnt latency pipelined. coi loop stays
// unroll-1 so live pressure is ~100 regs and there is no motive to stash
// anything in AGPRs between asm blocks.
// (R6 bench was an infra failure — container died before running; this is
// an unchanged resubmit of the experiment.)
// ---------------------------------------------------------------------------
#define XNP(ACC, X64, W64) do {                                   \
    uint32_t _wl = (uint32_t)(W64), _wh = (uint32_t)((W64) >> 32); \
    uint32_t _xl = (uint32_t)(X64), _xh = (uint32_t)((X64) >> 32); \
    uint32_t _t0, _t1;                                             \
    asm("v_xor_b32 %0, %3, %5\n\t"                                 \
        "v_xor_b32 %1, %4, %6\n\t"                                 \
        "v_bcnt_u32_b32 %2, %0, %2\n\t"                            \
        "v_bcnt_u32_b32 %2, %1, %2"                                \
        : "=&v"(_t0), "=&v"(_t1), "+v"(ACC)                        \
        : "s"(_wl), "s"(_wh), "v"(_xl), "v"(_xh));                 \
} while (0)

__global__ void __launch_bounds__(256, 4)
k_conv(const uint64_t* __restrict__ xbits, const uint64_t* __restrict__ wbits,
       const int* __restrict__ ctab, const float* __restrict__ beta_map,
       const float* __restrict__ alpha, const float* __restrict__ bias,
       float* __restrict__ out) {
    const int p   = blockIdx.x * 256 + (int)threadIdx.x;  // flat pixel
    const int grp = blockIdx.y;                            // cout group of 64
    const int n  = p / HW_;
    const int hw = p - n * HW_;
    const int h  = hw / W_;
    const int w  = hw - h * W_;

    // load 3x3x4wd window (36 u64) from the planar padded planes
    uint64_t xw[36];
#pragma unroll
    for (int wd = 0; wd < 4; ++wd) {
        const uint64_t* xp = xbits + ((size_t)wd * N_ + n) * PIMG_ + (size_t)h * PW_ + w;
#pragma unroll
        for (int r = 0; r < 3; ++r) {
            xw[wd * 9 + r * 3 + 0] = xp[r * PW_ + 0];
            xw[wd * 9 + r * 3 + 1] = xp[r * PW_ + 1];
            xw[wd * 9 + r * 3 + 2] = xp[r * PW_ + 2];
        }
    }

    const int rowcls = (h == 0) ? 0 : ((h == H_ - 1) ? 2 : 1);
    const int colcls = (w == 0) ? 0 : ((w == W_ - 1) ? 2 : 1);
    const int* crow = ctab + (rowcls * 3 + colcls) * 256 + grp * 64;
    const float bm = beta_map[p];
    float* op = out + (size_t)n * COUT_ * HW_ + (size_t)(grp * 64) * HW_ + hw;

#pragma unroll 1
    for (int coi = 0; coi < 64; ++coi) {
        const int co = grp * 64 + coi;
        const uint64_t* wr = wbits + (size_t)co * 36;   // wave-uniform -> s_load
        int a0 = 0, a1 = 0, a2 = 0, a3 = 0;
#pragma unroll
        for (int k = 0; k < 9; ++k) {
            XNP(a0, xw[k],      wr[k]);
            XNP(a1, xw[9 + k],  wr[9 + k]);
            XNP(a2, xw[18 + k], wr[18 + k]);
            XNP(a3, xw[27 + k], wr[27 + k]);
        }
        const int acc = (a0 + a1) + (a2 + a3);
        const int dot = 2304 - 2 * acc + crow[coi];
        float o = ((float)dot + bias[co]) * bm * alpha[co];
        o = fmaxf(o, 0.f);
        op[(size_t)coi * HW_] = o;
    }
}

// ---------------------------------------------------------------------------
// Workspace layout (bytes):
//   ps       @ 0        8192
//   pq       @ 8192     8192
//   a        @ 16384    1024
//   bb       @ 17408    1024
//   alpha    @ 18432    1024
//   ctab     @ 19456    9216
//   wbits    @ 28672    73728     ([co][wd][9] u64, 288 B contiguous per co)
//   xbits    @ 102400   3444736   (planar [wd][32][58][58] u64, memset 0)
//   m        @ 3547136  401408    (zeroed via memset; atomic-accumulated)
//   beta_map @ 3948544  401408
//   total    4349952
// ---------------------------------------------------------------------------
extern "C" void kernel_launch(void* const* d_in, const int* in_sizes, int n_in,
                              void* d_out, int out_size, void* d_ws, size_t ws_size,
                              hipStream_t stream) {
    (void)in_sizes; (void)n_in; (void)out_size; (void)ws_size;
    const float* x     = (const float*)d_in[0];
    const float* gamma = (const float*)d_in[1];
    const float* betab = (const float*)d_in[2];
    const float* Wt    = (const float*)d_in[3];
    const float* b     = (const float*)d_in[4];
    float* out = (float*)d_out;

    uint8_t* base = (uint8_t*)d_ws;
    float*    ps       = (float*)(base + 0);
    float*    pq       = (float*)(base + 8192);
    float*    a        = (float*)(base + 16384);
    float*    bb       = (float*)(base + 17408);
    float*    alpha    = (float*)(base + 18432);
    int*      ctab     = (int*)(base + 19456);
    uint64_t* wbits    = (uint64_t*)(base + 28672);
    uint64_t* xbits    = (uint64_t*)(base + 102400);
    float*    m        = (float*)(base + 3547136);
    float*    beta_map = (float*)(base + 3948544);

    k_bn_partial<<<2048, 256, 0, stream>>>(x, ps, pq);
    k_bn_final<<<1, 256, 0, stream>>>(ps, pq, gamma, betab, a, bb);
    k_wpack<<<COUT_, 256, 0, stream>>>(Wt, alpha, wbits, ctab);
    hipMemsetAsync(xbits, 0, (size_t)N_ * PIMG_ * 4 * sizeof(uint64_t), stream);
    hipMemsetAsync(m, 0, (size_t)NHW_ * sizeof(float), stream);
    k_mpack<<<dim3(NHW_ / 256, 4), 256, 0, stream>>>(x, a, bb, xbits, m);
    k_box<<<(NHW_ + 255) / 256, 256, 0, stream>>>(m, beta_map);
    k_conv<<<dim3(NHW_ / 256, 4), 256, 0, stream>>>(xbits, wbits, ctab, beta_map, alpha, b, out);
}